// Round 3
// baseline (435.417 us; speedup 1.0000x reference)
//
#include <hip/hip_runtime.h>
#include <math.h>

#define NN 48
#define CC 512
#define KK 64
#define PP 1600
#define EPSF 1e-12f

typedef short short8 __attribute__((ext_vector_type(8)));
typedef float f32x4 __attribute__((ext_vector_type(4)));

static __device__ __forceinline__ unsigned short f2bf(float f) {
    unsigned u = __float_as_uint(f);
    u += 0x7fffu + ((u >> 16) & 1u);   // round-to-nearest-even
    return (unsigned short)(u >> 16);
}
static __device__ __forceinline__ unsigned pack2(float a, float b) {
    return (unsigned)f2bf(a) | ((unsigned)f2bf(b) << 16);
}

// ---------------------------------------------------------------------------
// Kernel 1: fused norm + attn + logits MFMA-GEMM + softmax.
// grid (25, N) = 1200 blocks, block 256 (4 waves). Per block: 64 p, all 512 c
// in 8 chunks of 64 c. Ping-pong register prefetch: chunk cs+1's global loads
// are issued right after the write barrier and land during chunk cs's MFMA.
// Emits w'[n,k,p] bf16 (= softmax*hmp*invnorm), wsum[n,k] (fp32 atomics),
// and xbf = bf16(x) for kn_term1.
// ---------------------------------------------------------------------------
__global__ __launch_bounds__(256) void kn_logits(
    const float* __restrict__ x, const float* __restrict__ conv_w,
    const float* __restrict__ attn_w, const float* __restrict__ attn_b,
    unsigned short* __restrict__ wg, float* __restrict__ wsum,
    unsigned short* __restrict__ xbf)
{
    __shared__ unsigned short xt[64][68];    // [c_local][p] bf16 (136B rows: 8B-aligned, write-conflict-free)
    __shared__ unsigned short cwb[64][72];   // [k][c_local] bf16 (144B rows: 16B-aligned b128 A-frags)
    __shared__ float attn_l[CC];
    __shared__ float red[16][66];
    __shared__ float invn_l[64];
    __shared__ float hmp_l[64];

    const int n = blockIdx.y, p0 = blockIdx.x * 64, tid = threadIdx.x;
    const int pq = tid & 15, crow = tid >> 4;      // x staging: p-quad, c-row
    const int kr = tid >> 2, cq = tid & 3;         // conv_w staging
    const int wave = tid >> 6, lane = tid & 63;
    const int lq = lane >> 4, lm = lane & 15;      // MFMA lane decomposition
    const int pw = wave * 16 + lm;                 // this lane's p column

    for (int i = tid; i < CC; i += 256) attn_l[i] = attn_w[i];

    f32x4 acc[4];
#pragma unroll
    for (int mt = 0; mt < 4; ++mt) acc[mt] = (f32x4){0.f, 0.f, 0.f, 0.f};
    float ss[4] = {0.f, 0.f, 0.f, 0.f};
    float ad[4] = {0.f, 0.f, 0.f, 0.f};

    const float* xb = x + (size_t)n * CC * PP + p0;

    float4 xr[2][4], wr4[2][4];
#pragma unroll
    for (int j = 0; j < 4; ++j) {       // prefetch chunk 0
        xr[0][j]  = *(const float4*)(xb + (size_t)(crow + 16 * j) * PP + 4 * pq);
        wr4[0][j] = *(const float4*)(conv_w + kr * CC + cq * 16 + 4 * j);
    }
    __syncthreads();                    // attn_l ready

    for (int cs = 0; cs < 8; ++cs) {
        const int cur = cs & 1, nxt = cur ^ 1, c0 = cs * 64;
        // consume prefetched regs: stats + bf16 pack + LDS write + xbf store
#pragma unroll
        for (int j = 0; j < 4; ++j) {
            const int cl = crow + 16 * j;
            const float4 v = xr[cur][j];
            const float aw = attn_l[c0 + cl];
            ss[0] += v.x * v.x; ss[1] += v.y * v.y;
            ss[2] += v.z * v.z; ss[3] += v.w * v.w;
            ad[0] += fmaxf(v.x, 0.f) * aw; ad[1] += fmaxf(v.y, 0.f) * aw;
            ad[2] += fmaxf(v.z, 0.f) * aw; ad[3] += fmaxf(v.w, 0.f) * aw;
            const uint2 u = {pack2(v.x, v.y), pack2(v.z, v.w)};
            *(uint2*)&xt[cl][4 * pq] = u;
            if (xbf)
                *(uint2*)(xbf + ((size_t)n * CC + c0 + cl) * PP + p0 + 4 * pq) = u;
            const float4 w4 = wr4[cur][j];
            const uint2 uw = {pack2(w4.x, w4.y), pack2(w4.z, w4.w)};
            *(uint2*)&cwb[kr][cq * 16 + 4 * j] = uw;
        }
        __syncthreads();
        if (cs < 7) {                   // issue next chunk's loads: land during MFMA
            const int c1 = c0 + 64;
#pragma unroll
            for (int j = 0; j < 4; ++j) {
                xr[nxt][j]  = *(const float4*)(xb + (size_t)(c1 + crow + 16 * j) * PP + 4 * pq);
                wr4[nxt][j] = *(const float4*)(conv_w + kr * CC + c1 + cq * 16 + 4 * j);
            }
        }
#pragma unroll
        for (int ks = 0; ks < 2; ++ks) {
            short8 bv;
#pragma unroll
            for (int j = 0; j < 8; ++j) bv[j] = (short)xt[ks * 32 + lq * 8 + j][pw];
#pragma unroll
            for (int mt = 0; mt < 4; ++mt) {
                const short8 af = *(const short8*)&cwb[mt * 16 + lm][ks * 32 + lq * 8];
                acc[mt] = __builtin_amdgcn_mfma_f32_16x16x32_bf16(af, bv, acc[mt], 0, 0, 0);
            }
        }
        __syncthreads();
    }

    // block reductions across the 16 c-row groups: invnorm and hmp per p
#pragma unroll
    for (int j = 0; j < 4; ++j) red[crow][4 * pq + j] = ss[j];
    __syncthreads();
    if (tid < 64) {
        float S = 0.f;
#pragma unroll
        for (int l = 0; l < 16; ++l) S += red[l][tid];
        invn_l[tid] = 1.f / fmaxf(sqrtf(S), EPSF);
    }
    __syncthreads();
#pragma unroll
    for (int j = 0; j < 4; ++j) red[crow][4 * pq + j] = ad[j];
    __syncthreads();
    if (tid < 64) {
        float A = 0.f;
#pragma unroll
        for (int l = 0; l < 16; ++l) A += red[l][tid];
        hmp_l[tid] = fmaxf(A + attn_b[0], 0.f);
    }
    __syncthreads();

    // softmax over k=64 per p, in registers (C-layout: k spread over lq,mt,r)
    const float inv = invn_l[pw];
    const float hp  = hmp_l[pw];
    float mx = -1e30f;
#pragma unroll
    for (int mt = 0; mt < 4; ++mt)
#pragma unroll
        for (int r = 0; r < 4; ++r) {
            const float l = acc[mt][r] * inv;
            acc[mt][r] = l;
            mx = fmaxf(mx, l);
        }
    mx = fmaxf(mx, __shfl_xor(mx, 16));
    mx = fmaxf(mx, __shfl_xor(mx, 32));
    float s = 0.f;
#pragma unroll
    for (int mt = 0; mt < 4; ++mt)
#pragma unroll
        for (int r = 0; r < 4; ++r) {
            const float e = __expf(acc[mt][r] - mx);
            acc[mt][r] = e;
            s += e;
        }
    s += __shfl_xor(s, 16);
    s += __shfl_xor(s, 32);
    const float sden = hp / s;

    // w = e*hmp/sum; wsum via lm-shuffle + atomics; store w' = w*invn (bf16)
#pragma unroll
    for (int mt = 0; mt < 4; ++mt)
#pragma unroll
        for (int r = 0; r < 4; ++r) {
            const float w = acc[mt][r] * sden;
            float wk = w;
#pragma unroll
            for (int o = 1; o < 16; o <<= 1) wk += __shfl_xor(wk, o);
            const int k = mt * 16 + lq * 4 + r;
            if (lm == 0) atomicAdd(&wsum[n * KK + k], wk);
            wg[((size_t)n * KK + k) * PP + p0 + pw] = f2bf(w * inv);
        }
}

// ---------------------------------------------------------------------------
// Kernel 2: term1[k,c] = sum_p w'[k,p] * x[c,p] via MFMA (contraction over p;
// both operands p-contiguous -> b128 fragments). grid (4 c-chunks, N, 4 p-
// chunks) = 768 blocks. Software-pipelined staging. XB: x from bf16 sidecar;
// else convert fp32 x inline.
// ---------------------------------------------------------------------------
template <bool XB>
__global__ __launch_bounds__(256) void kn_term1(
    const float* __restrict__ xf, const unsigned short* __restrict__ xbf,
    const unsigned short* __restrict__ wgq, float* __restrict__ term1p)
{
    __shared__ unsigned short wt[64][40];    // [k][32p] bf16
    __shared__ unsigned short xt2[128][40];  // [c_local][32p] bf16
    const int c0 = blockIdx.x * 128, n = blockIdx.y, ph = blockIdx.z;
    const int tid = threadIdx.x;
    const int wave = tid >> 6, lane = tid & 63, lq = lane >> 4, lm = lane & 15;
    const int koff = (wave >> 1) * 32, coff = (wave & 1) * 64;
    const int s_begin = (50 * ph) >> 2, s_end = (50 * (ph + 1)) >> 2;

    const int rA = tid >> 2, cqA = tid & 3;
    const int rB0 = tid >> 2, cqB0 = tid & 3;
    const int rB1 = (256 + tid) >> 2, cqB1 = tid & 3;

    f32x4 acc[2][4];
#pragma unroll
    for (int mt = 0; mt < 2; ++mt)
#pragma unroll
        for (int nt = 0; nt < 4; ++nt) acc[mt][nt] = (f32x4){0.f, 0.f, 0.f, 0.f};

    const unsigned short* wb = wgq + (size_t)n * KK * PP;

    auto ldA = [&](int p0) -> uint4 {
        return *(const uint4*)(wb + (size_t)rA * PP + p0 + cqA * 8);
    };
    auto ldB = [&](int p0, int row, int cq) -> uint4 {
        if (XB) {
            return *(const uint4*)(xbf + ((size_t)n * CC + c0 + row) * PP + p0 + cq * 8);
        } else {
            const float* sp = xf + ((size_t)n * CC + c0 + row) * PP + p0 + cq * 8;
            float4 a = *(const float4*)sp, b = *(const float4*)(sp + 4);
            return make_uint4(pack2(a.x, a.y), pack2(a.z, a.w),
                              pack2(b.x, b.y), pack2(b.z, b.w));
        }
    };

    uint4 pa = ldA(s_begin * 32);
    uint4 pb0 = ldB(s_begin * 32, rB0, cqB0);
    uint4 pb1 = ldB(s_begin * 32, rB1, cqB1);

    for (int ps = s_begin; ps < s_end; ++ps) {
        *(uint4*)&wt[rA][cqA * 8] = pa;
        *(uint4*)&xt2[rB0][cqB0 * 8] = pb0;
        *(uint4*)&xt2[rB1][cqB1 * 8] = pb1;
        __syncthreads();
        uint4 na, nb0, nb1;
        if (ps + 1 < s_end) {
            const int p1 = (ps + 1) * 32;
            na = ldA(p1); nb0 = ldB(p1, rB0, cqB0); nb1 = ldB(p1, rB1, cqB1);
        }
        short8 af[2], bv[4];
#pragma unroll
        for (int mt = 0; mt < 2; ++mt)
            af[mt] = *(const short8*)&wt[koff + mt * 16 + lm][lq * 8];
#pragma unroll
        for (int nt = 0; nt < 4; ++nt)
            bv[nt] = *(const short8*)&xt2[coff + nt * 16 + lm][lq * 8];
#pragma unroll
        for (int mt = 0; mt < 2; ++mt)
#pragma unroll
            for (int nt = 0; nt < 4; ++nt)
                acc[mt][nt] = __builtin_amdgcn_mfma_f32_16x16x32_bf16(
                    af[mt], bv[nt], acc[mt][nt], 0, 0, 0);
        __syncthreads();
        pa = na; pb0 = nb0; pb1 = nb1;
    }

    float* ob = term1p + ((size_t)ph * NN + n) * KK * CC;
#pragma unroll
    for (int mt = 0; mt < 2; ++mt)
#pragma unroll
        for (int r = 0; r < 4; ++r) {
            const int k = koff + mt * 16 + lq * 4 + r;
#pragma unroll
            for (int nt = 0; nt < 4; ++nt)
                ob[(size_t)k * CC + c0 + coff + nt * 16 + lm] = acc[mt][nt][r];
        }
}

// ---------------------------------------------------------------------------
// Kernel 3: vlad = sum(term1 partials) - wsum*centroids; intra L2-normalize;
// per-n global sumsq. grid (K, N), block 128.
// ---------------------------------------------------------------------------
__global__ __launch_bounds__(128) void kn_vlad(
    const float* __restrict__ term1p, const float* __restrict__ wsum,
    const float* __restrict__ cent, float* __restrict__ out,
    float* __restrict__ nsum)
{
    const int k = blockIdx.x, n = blockIdx.y, tid = threadIdx.x;
    const size_t base = ((size_t)n * KK + k) * CC;
    const size_t NKC = (size_t)NN * KK * CC;
    const float ws = wsum[n * KK + k];
    const int c = tid * 4;

    float4 ce = *(const float4*)(cent + (size_t)k * CC + c);
    float4 v = {-ws * ce.x, -ws * ce.y, -ws * ce.z, -ws * ce.w};
#pragma unroll
    for (int h = 0; h < 4; ++h) {
        float4 a = *(const float4*)(term1p + h * NKC + base + c);
        v.x += a.x; v.y += a.y; v.z += a.z; v.w += a.w;
    }

    float s = v.x * v.x + v.y * v.y + v.z * v.z + v.w * v.w;
#pragma unroll
    for (int o = 32; o >= 1; o >>= 1) s += __shfl_down(s, o, 64);

    __shared__ float rb[2];
    __shared__ float sinv;
    if ((tid & 63) == 0) rb[tid >> 6] = s;
    __syncthreads();
    if (tid == 0) {
        const float S = rb[0] + rb[1];
        const float inv = 1.f / fmaxf(sqrtf(S), EPSF);
        sinv = inv;
        atomicAdd(&nsum[n], S * inv * inv);
    }
    __syncthreads();
    const float inv = sinv;
    float4 o4 = {v.x * inv, v.y * inv, v.z * inv, v.w * inv};
    *(float4*)(out + base + c) = o4;
}

// ---------------------------------------------------------------------------
// Kernel 4: global L2 normalize per n.
// ---------------------------------------------------------------------------
__global__ __launch_bounds__(256) void kn_scale(
    float* __restrict__ out, const float* __restrict__ nsum)
{
    const int n = blockIdx.y;
    const size_t off = ((size_t)blockIdx.x * 256 + threadIdx.x) * 4;
    const float g = 1.f / fmaxf(sqrtf(nsum[n]), EPSF);
    float4 v = *(float4*)(out + (size_t)n * KK * CC + off);
    v.x *= g; v.y *= g; v.z *= g; v.w *= g;
    *(float4*)(out + (size_t)n * KK * CC + off) = v;
}

extern "C" void kernel_launch(void* const* d_in, const int* in_sizes, int n_in,
                              void* d_out, int out_size, void* d_ws, size_t ws_size,
                              hipStream_t stream)
{
    (void)in_sizes; (void)n_in; (void)out_size;
    const float* x      = (const float*)d_in[0];
    const float* conv_w = (const float*)d_in[1];
    const float* attn_w = (const float*)d_in[2];
    const float* attn_b = (const float*)d_in[3];
    const float* cent   = (const float*)d_in[4];
    float* out = (float*)d_out;

    // ws layout: term1p[4][N][K][C] f32 | wsum f32 | nsum f32(pad) | wg bf16 | xbf bf16
    char* w = (char*)d_ws;
    float* term1p = (float*)w;            w += (size_t)4 * NN * KK * CC * 4;
    float* wsum   = (float*)w;            w += (size_t)NN * KK * 4;
    float* nsum   = (float*)w;            w += 256;
    unsigned short* wg  = (unsigned short*)w; w += (size_t)NN * KK * PP * 2;
    unsigned short* xbf = (unsigned short*)w;
    const size_t need_xb = (size_t)(w - (char*)d_ws) + (size_t)NN * CC * PP * 2;
    const bool xb = ws_size >= need_xb;

    hipMemsetAsync(wsum, 0, NN * KK * sizeof(float), stream);
    hipMemsetAsync(nsum, 0, NN * sizeof(float), stream);

    kn_logits<<<dim3(25, NN), 256, 0, stream>>>(x, conv_w, attn_w, attn_b,
                                                wg, wsum, xb ? xbf : nullptr);
    if (xb)
        kn_term1<true><<<dim3(4, NN, 4), 256, 0, stream>>>(x, xbf, wg, term1p);
    else
        kn_term1<false><<<dim3(4, NN, 4), 256, 0, stream>>>(x, xbf, wg, term1p);
    kn_vlad <<<dim3(KK, NN), 128, 0, stream>>>(term1p, wsum, cent, out, nsum);
    kn_scale<<<dim3(32, NN), 256, 0, stream>>>(out, nsum);
}

// Round 5
// 322.759 us; speedup vs baseline: 1.3490x; 1.3490x over previous
//
#include <hip/hip_runtime.h>
#include <math.h>

#define NN 48
#define CC 512
#define KK 64
#define PP 1600
#define PT 13            // 13 tiles of 128 p (padded to 1664)
#define EPSF 1e-12f

typedef short short8 __attribute__((ext_vector_type(8)));
typedef float f32x4 __attribute__((ext_vector_type(4)));

static __device__ __forceinline__ unsigned short f2bf(float f) {
    unsigned u = __float_as_uint(f);
    u += 0x7fffu + ((u >> 16) & 1u);   // round-to-nearest-even
    return (unsigned short)(u >> 16);
}
static __device__ __forceinline__ unsigned pack2(float a, float b) {
    return (unsigned)f2bf(a) | ((unsigned)f2bf(b) << 16);
}

// ---------------------------------------------------------------------------
// Kernel 1: fused norm + attn + logits MFMA-GEMM + softmax.
// grid (13, N), block 512 (8 waves). p-tile 128 (256B-aligned output rows).
// Single-barrier LDS double-buffer: consume regs->LDS[b], issue next chunk's
// global loads (consumed across the barrier -> compiler can't sink them),
// barrier, MFMA on LDS[b] while loads fly.
// Outputs TILED: wg[n][pt][k][128], xbf[n][pt][c][128] -- each block writes
// one fully-contiguous region (no partial-line RMW).
// NOTE: xt row stride 132 (>=128 p + pad; R4's 68 was a buffer overflow).
// ---------------------------------------------------------------------------
__global__ __launch_bounds__(512) void kn_logits(
    const float* __restrict__ x, const float* __restrict__ conv_w,
    const float* __restrict__ attn_w, const float* __restrict__ attn_b,
    unsigned short* __restrict__ wg, float* __restrict__ wsum,
    unsigned short* __restrict__ xbf)
{
    __shared__ unsigned short xt[2][64][132];   // [buf][c_local][p] bf16 (264B rows)
    __shared__ unsigned short cwb[2][64][72];   // [buf][k][c_local] bf16 (144B rows)
    __shared__ float attn_l[CC];
    __shared__ float red[16][128];
    __shared__ float invn_l[128];
    __shared__ float hmp_l[128];

    const int n = blockIdx.y, pt = blockIdx.x, p0 = pt * 128;
    const int tid = threadIdx.x;
    const int pq = tid & 31, crow = tid >> 5;      // x staging: 32 p-quads x 16 c-rows
    const int kr = tid >> 3, cq8 = tid & 7;        // conv_w staging: 64 k x 8 c-octs
    const int wave = tid >> 6, lane = tid & 63;
    const int lq = lane >> 4, lm = lane & 15;      // MFMA lane decomposition
    const int pw = wave * 16 + lm;                 // this lane's p column (0..127)
    const bool pv4 = (p0 + 4 * pq) < PP;           // float4 fully valid (PP%4==0)

    for (int i = tid; i < CC; i += 512) attn_l[i] = attn_w[i];

    f32x4 acc[4];
#pragma unroll
    for (int mt = 0; mt < 4; ++mt) acc[mt] = (f32x4){0.f, 0.f, 0.f, 0.f};
    float ss[4] = {0.f, 0.f, 0.f, 0.f};
    float ad[4] = {0.f, 0.f, 0.f, 0.f};

    const float* xb = x + (size_t)n * CC * PP + p0;
    unsigned short* xrow = xbf ? xbf + ((size_t)n * PT + pt) * CC * 128 : nullptr;

    float4 xr[4], wa, wb;
#pragma unroll
    for (int j = 0; j < 4; ++j)
        xr[j] = pv4 ? *(const float4*)(xb + (size_t)(crow + 16 * j) * PP + 4 * pq)
                    : make_float4(0.f, 0.f, 0.f, 0.f);
    wa = *(const float4*)(conv_w + kr * CC + cq8 * 8);
    wb = *(const float4*)(conv_w + kr * CC + cq8 * 8 + 4);
    __syncthreads();                    // attn_l ready

    for (int cs = 0; cs < 8; ++cs) {
        const int bsel = cs & 1, c0 = cs * 64;
        // consume prefetched regs: stats + bf16 pack + LDS write + xbf store
#pragma unroll
        for (int j = 0; j < 4; ++j) {
            const int cl = crow + 16 * j, cg = c0 + cl;
            const float4 v = xr[j];
            const float aw = attn_l[cg];
            ss[0] += v.x * v.x; ss[1] += v.y * v.y;
            ss[2] += v.z * v.z; ss[3] += v.w * v.w;
            ad[0] += fmaxf(v.x, 0.f) * aw; ad[1] += fmaxf(v.y, 0.f) * aw;
            ad[2] += fmaxf(v.z, 0.f) * aw; ad[3] += fmaxf(v.w, 0.f) * aw;
            const uint2 u = {pack2(v.x, v.y), pack2(v.z, v.w)};
            *(uint2*)&xt[bsel][cl][4 * pq] = u;
            if (xrow) *(uint2*)(xrow + (size_t)cg * 128 + 4 * pq) = u;
        }
        {
            const uint2 u0 = {pack2(wa.x, wa.y), pack2(wa.z, wa.w)};
            const uint2 u1 = {pack2(wb.x, wb.y), pack2(wb.z, wb.w)};
            *(uint2*)&cwb[bsel][kr][cq8 * 8] = u0;
            *(uint2*)&cwb[bsel][kr][cq8 * 8 + 4] = u1;
        }
        if (cs < 7) {                   // issue next chunk's loads; land during MFMA
            const int c1 = c0 + 64;
#pragma unroll
            for (int j = 0; j < 4; ++j)
                xr[j] = pv4 ? *(const float4*)(xb + (size_t)(c1 + crow + 16 * j) * PP + 4 * pq)
                            : make_float4(0.f, 0.f, 0.f, 0.f);
            wa = *(const float4*)(conv_w + kr * CC + c1 + cq8 * 8);
            wb = *(const float4*)(conv_w + kr * CC + c1 + cq8 * 8 + 4);
        }
        __syncthreads();
        // MFMA on buffer bsel (next iteration writes bsel^1: no barrier needed)
#pragma unroll
        for (int ks = 0; ks < 2; ++ks) {
            short8 bv;
#pragma unroll
            for (int j = 0; j < 8; ++j) bv[j] = (short)xt[bsel][ks * 32 + lq * 8 + j][pw];
#pragma unroll
            for (int mt = 0; mt < 4; ++mt) {
                const short8 af = *(const short8*)&cwb[bsel][mt * 16 + lm][ks * 32 + lq * 8];
                acc[mt] = __builtin_amdgcn_mfma_f32_16x16x32_bf16(af, bv, acc[mt], 0, 0, 0);
            }
        }
    }

    // block reductions across 16 c-row groups: invnorm and hmp per p
#pragma unroll
    for (int j = 0; j < 4; ++j) red[crow][4 * pq + j] = ss[j];
    __syncthreads();
    if (tid < 128) {
        float S = 0.f;
#pragma unroll
        for (int l = 0; l < 16; ++l) S += red[l][tid];
        invn_l[tid] = 1.f / fmaxf(sqrtf(S), EPSF);
    }
    __syncthreads();
#pragma unroll
    for (int j = 0; j < 4; ++j) red[crow][4 * pq + j] = ad[j];
    __syncthreads();
    if (tid < 128) {
        float A = 0.f;
#pragma unroll
        for (int l = 0; l < 16; ++l) A += red[l][tid];
        hmp_l[tid] = fmaxf(A + attn_b[0], 0.f);
    }
    __syncthreads();

    // softmax over k=64 per p, in registers (k spread over mt, lq, r)
    const float inv = invn_l[pw];
    const float hp = (p0 + pw < PP) ? hmp_l[pw] : 0.f;   // pad p -> w = 0
    float mx = -1e30f;
#pragma unroll
    for (int mt = 0; mt < 4; ++mt)
#pragma unroll
        for (int r = 0; r < 4; ++r) {
            const float l = acc[mt][r] * inv;
            acc[mt][r] = l;
            mx = fmaxf(mx, l);
        }
    mx = fmaxf(mx, __shfl_xor(mx, 16));
    mx = fmaxf(mx, __shfl_xor(mx, 32));
    float s = 0.f;
#pragma unroll
    for (int mt = 0; mt < 4; ++mt)
#pragma unroll
        for (int r = 0; r < 4; ++r) {
            const float e = __expf(acc[mt][r] - mx);
            acc[mt][r] = e;
            s += e;
        }
    s += __shfl_xor(s, 16);
    s += __shfl_xor(s, 32);
    const float sden = hp / s;

    unsigned short* wrow = wg + ((size_t)n * PT + pt) * KK * 128;
#pragma unroll
    for (int mt = 0; mt < 4; ++mt)
#pragma unroll
        for (int r = 0; r < 4; ++r) {
            const float w = acc[mt][r] * sden;
            float wk = w;
#pragma unroll
            for (int o = 1; o < 16; o <<= 1) wk += __shfl_xor(wk, o);
            const int k = mt * 16 + lq * 4 + r;
            if (lm == 0) atomicAdd(&wsum[n * KK + k], wk);
            wrow[(size_t)k * 128 + pw] = f2bf(w * inv);
        }
}

// ---------------------------------------------------------------------------
// Kernel 2: term1[k,c] = sum_p w'[k,p]*x[c,p] via MFMA over tiled bf16 inputs.
// grid (4 c-chunks, N, 4 p-groups); p-groups own tiles {0..3},{4..6},{7..9},
// {10..12}; each tile = 4 stages of 32 p. Single-barrier LDS double-buffer
// with register prefetch. Pad p contribute 0 (wg/xbf pads are 0).
// ---------------------------------------------------------------------------
template <bool XB>
__global__ __launch_bounds__(256) void kn_term1(
    const float* __restrict__ xf, const unsigned short* __restrict__ xbf,
    const unsigned short* __restrict__ wgq, float* __restrict__ term1p)
{
    __shared__ unsigned short wt[2][64][40];     // [buf][k][32p]
    __shared__ unsigned short xt2[2][128][40];   // [buf][c_local][32p]
    const int c0 = blockIdx.x * 128, n = blockIdx.y, ph = blockIdx.z;
    const int tid = threadIdx.x;
    const int wave = tid >> 6, lane = tid & 63, lq = lane >> 4, lm = lane & 15;
    const int koff = (wave >> 1) * 32, coff = (wave & 1) * 64;
    const int tb = (ph == 0) ? 0 : 1 + 3 * ph;   // tile base: {0,4,7,10}
    const int ns = ((ph == 0) ? 4 : 3) * 4;      // stages of 32 p
    const int rA = tid >> 2, cq = tid & 3;

    f32x4 acc[2][4];
#pragma unroll
    for (int mt = 0; mt < 2; ++mt)
#pragma unroll
        for (int nt = 0; nt < 4; ++nt) acc[mt][nt] = (f32x4){0.f, 0.f, 0.f, 0.f};

    auto ldA = [&](int s) -> uint4 {
        const int ptl = tb + (s >> 2), q = s & 3;
        return *(const uint4*)(wgq + (((size_t)n * PT + ptl) * KK + rA) * 128 + q * 32 + cq * 8);
    };
    auto ldB = [&](int s, int row) -> uint4 {
        const int ptl = tb + (s >> 2), q = s & 3;
        if (XB) {
            return *(const uint4*)(xbf + (((size_t)n * PT + ptl) * CC + c0 + row) * 128 + q * 32 + cq * 8);
        } else {
            const int pg = ptl * 128 + q * 32 + cq * 8;
            if (pg >= PP) return make_uint4(0u, 0u, 0u, 0u);
            const float* sp = xf + ((size_t)n * CC + c0 + row) * PP + pg;
            const float4 a = *(const float4*)sp, b = *(const float4*)(sp + 4);
            return make_uint4(pack2(a.x, a.y), pack2(a.z, a.w),
                              pack2(b.x, b.y), pack2(b.z, b.w));
        }
    };

    uint4 pa = ldA(0), pb0 = ldB(0, rA), pb1 = ldB(0, 64 + rA);

    for (int s = 0; s < ns; ++s) {
        const int bsel = s & 1;
        *(uint4*)&wt[bsel][rA][cq * 8] = pa;
        *(uint4*)&xt2[bsel][rA][cq * 8] = pb0;
        *(uint4*)&xt2[bsel][64 + rA][cq * 8] = pb1;
        uint4 na = {0, 0, 0, 0}, nb0 = {0, 0, 0, 0}, nb1 = {0, 0, 0, 0};
        if (s + 1 < ns) {
            na = ldA(s + 1); nb0 = ldB(s + 1, rA); nb1 = ldB(s + 1, 64 + rA);
        }
        __syncthreads();
        short8 af[2], bv[4];
#pragma unroll
        for (int mt = 0; mt < 2; ++mt)
            af[mt] = *(const short8*)&wt[bsel][koff + mt * 16 + lm][lq * 8];
#pragma unroll
        for (int nt = 0; nt < 4; ++nt)
            bv[nt] = *(const short8*)&xt2[bsel][coff + nt * 16 + lm][lq * 8];
#pragma unroll
        for (int mt = 0; mt < 2; ++mt)
#pragma unroll
            for (int nt = 0; nt < 4; ++nt)
                acc[mt][nt] = __builtin_amdgcn_mfma_f32_16x16x32_bf16(
                    af[mt], bv[nt], acc[mt][nt], 0, 0, 0);
        pa = na; pb0 = nb0; pb1 = nb1;
        // next iteration writes buffer bsel^1 -> safe without a second barrier
    }

    float* ob = term1p + ((size_t)ph * NN + n) * KK * CC;
#pragma unroll
    for (int mt = 0; mt < 2; ++mt)
#pragma unroll
        for (int r = 0; r < 4; ++r) {
            const int k = koff + mt * 16 + lq * 4 + r;
#pragma unroll
            for (int nt = 0; nt < 4; ++nt)
                ob[(size_t)k * CC + c0 + coff + nt * 16 + lm] = acc[mt][nt][r];
        }
}

// ---------------------------------------------------------------------------
// Kernel 3: vlad = sum(term1 partials) - wsum*centroids; intra L2-normalize;
// per-n global sumsq. grid (K, N), block 128.
// ---------------------------------------------------------------------------
__global__ __launch_bounds__(128) void kn_vlad(
    const float* __restrict__ term1p, const float* __restrict__ wsum,
    const float* __restrict__ cent, float* __restrict__ out,
    float* __restrict__ nsum)
{
    const int k = blockIdx.x, n = blockIdx.y, tid = threadIdx.x;
    const size_t base = ((size_t)n * KK + k) * CC;
    const size_t NKC = (size_t)NN * KK * CC;
    const float ws = wsum[n * KK + k];
    const int c = tid * 4;

    float4 ce = *(const float4*)(cent + (size_t)k * CC + c);
    float4 v = {-ws * ce.x, -ws * ce.y, -ws * ce.z, -ws * ce.w};
#pragma unroll
    for (int h = 0; h < 4; ++h) {
        float4 a = *(const float4*)(term1p + h * NKC + base + c);
        v.x += a.x; v.y += a.y; v.z += a.z; v.w += a.w;
    }

    float s = v.x * v.x + v.y * v.y + v.z * v.z + v.w * v.w;
#pragma unroll
    for (int o = 32; o >= 1; o >>= 1) s += __shfl_down(s, o, 64);

    __shared__ float rb[2];
    __shared__ float sinv;
    if ((tid & 63) == 0) rb[tid >> 6] = s;
    __syncthreads();
    if (tid == 0) {
        const float S = rb[0] + rb[1];
        const float inv = 1.f / fmaxf(sqrtf(S), EPSF);
        sinv = inv;
        atomicAdd(&nsum[n], S * inv * inv);
    }
    __syncthreads();
    const float inv = sinv;
    float4 o4 = {v.x * inv, v.y * inv, v.z * inv, v.w * inv};
    *(float4*)(out + base + c) = o4;
}

// ---------------------------------------------------------------------------
// Kernel 4: global L2 normalize per n.
// ---------------------------------------------------------------------------
__global__ __launch_bounds__(256) void kn_scale(
    float* __restrict__ out, const float* __restrict__ nsum)
{
    const int n = blockIdx.y;
    const size_t off = ((size_t)blockIdx.x * 256 + threadIdx.x) * 4;
    const float g = 1.f / fmaxf(sqrtf(nsum[n]), EPSF);
    float4 v = *(float4*)(out + (size_t)n * KK * CC + off);
    v.x *= g; v.y *= g; v.z *= g; v.w *= g;
    *(float4*)(out + (size_t)n * KK * CC + off) = v;
}

extern "C" void kernel_launch(void* const* d_in, const int* in_sizes, int n_in,
                              void* d_out, int out_size, void* d_ws, size_t ws_size,
                              hipStream_t stream)
{
    (void)in_sizes; (void)n_in; (void)out_size;
    const float* x      = (const float*)d_in[0];
    const float* conv_w = (const float*)d_in[1];
    const float* attn_w = (const float*)d_in[2];
    const float* attn_b = (const float*)d_in[3];
    const float* cent   = (const float*)d_in[4];
    float* out = (float*)d_out;

    // ws: term1p[4][N][K][C] f32 | wsum | nsum | wg bf16 tiled | xbf bf16 tiled
    char* w = (char*)d_ws;
    float* term1p = (float*)w;            w += (size_t)4 * NN * KK * CC * 4;
    float* wsum   = (float*)w;            w += (size_t)NN * KK * 4;
    float* nsum   = (float*)w;            w += 256;
    unsigned short* wg  = (unsigned short*)w; w += (size_t)NN * PT * KK * 128 * 2;
    unsigned short* xbf = (unsigned short*)w;
    const size_t need_xb = (size_t)(w - (char*)d_ws) + (size_t)NN * PT * CC * 128 * 2;
    const bool xb = ws_size >= need_xb;

    hipMemsetAsync(wsum, 0, NN * KK * sizeof(float), stream);
    hipMemsetAsync(nsum, 0, NN * sizeof(float), stream);

    kn_logits<<<dim3(PT, NN), 512, 0, stream>>>(x, conv_w, attn_w, attn_b,
                                                wg, wsum, xb ? xbf : nullptr);
    if (xb)
        kn_term1<true><<<dim3(4, NN, 4), 256, 0, stream>>>(x, xbf, wg, term1p);
    else
        kn_term1<false><<<dim3(4, NN, 4), 256, 0, stream>>>(x, xbf, wg, term1p);
    kn_vlad <<<dim3(KK, NN), 128, 0, stream>>>(term1p, wsum, cent, out, nsum);
    kn_scale<<<dim3(32, NN), 256, 0, stream>>>(out, nsum);
}